// Round 1
// baseline (108.227 us; speedup 1.0000x reference)
//
#include <hip/hip_runtime.h>
#include <hip/hip_bf16.h>
#include <float.h>

// Problem constants (from reference): B=4, N=8, C=256, H=128, W=128, D=128
#define B_ 4
#define N_ 8
#define C_ 256
#define H_ 128
#define W_ 128
#define D_ 128

// ---------------------------------------------------------------------------
// Kernel 1: ROI max-pool.
// grid = 32 boxes * 64 channel-groups = 2048 blocks, 256 threads (4 waves).
// Each wave handles one channel of one box: lanes stride the flattened ROI
// (inner dim = x, contiguous -> coalesced within rows), then shfl-max reduce.
// pooled layout: [box(=b*N+n)][c]  (32 x 256 floats) in d_ws.
// ---------------------------------------------------------------------------
__global__ __launch_bounds__(256) void roi_pool_kernel(
    const float* __restrict__ enc,     // [B][C][H][W]
    const float* __restrict__ bboxes,  // [B][N][4]
    float* __restrict__ pooled)        // [32][256]
{
    const int block = blockIdx.x;
    const int box   = block >> 6;     // 0..31  (= b*N + n)
    const int cg    = block & 63;     // channel group of 4
    const int wave  = threadIdx.x >> 6;
    const int lane  = threadIdx.x & 63;
    const int c     = cg * 4 + wave;
    const int b     = box >> 3;       // box / N
    // box % N is n; enc index only needs b and c.

    const float* bb = bboxes + box * 4;
    // Replicate reference exactly: truncate-to-int, then integer div by 2.
    const int xc = (int)(bb[0] * (float)W_);
    const int yc = (int)(bb[1] * (float)H_);
    const int hw = ((int)(bb[2] * (float)W_)) / 2;
    const int hh = ((int)(bb[3] * (float)H_)) / 2;
    int x0 = xc - hw, x1 = xc + hw;   // inclusive
    int y0 = yc - hh, y1 = yc + hh;   // inclusive
    x0 = max(0, x0); x1 = min(W_ - 1, x1);
    y0 = max(0, y0); y1 = min(H_ - 1, y1);
    const int rw = x1 - x0 + 1;
    const int rh = y1 - y0 + 1;
    const int total = rw * rh;

    const float* base = enc + ((b * C_ + c) * H_ + y0) * W_ + x0;

    float m = -FLT_MAX;
    for (int idx = lane; idx < total; idx += 64) {
        const int r   = idx / rw;
        const int col = idx - r * rw;
        m = fmaxf(m, base[r * W_ + col]);
    }
    // wave-wide max reduce (wave = 64 lanes on gfx950)
    #pragma unroll
    for (int off = 32; off; off >>= 1)
        m = fmaxf(m, __shfl_down(m, off));
    if (lane == 0)
        pooled[box * C_ + c] = m;
}

// ---------------------------------------------------------------------------
// Kernel 2: fused MLP.  grid = 32 blocks (one per box), 128 threads.
// h1[j] = b1[j] + dot(pooled[i][:], w1[j][:])      (float4 inner loop)
// out[j'] = sigmoid(b2[j'] + dot(h1, w2[j'][:]))   (wave-0 shuffle reduce)
// Output written transposed: [N][B][4].
// ---------------------------------------------------------------------------
__global__ __launch_bounds__(128) void mlp_kernel(
    const float* __restrict__ pooled,  // [32][256]
    const float* __restrict__ w1,      // [128][256]
    const float* __restrict__ b1,      // [128]
    const float* __restrict__ w2,      // [4][128]
    const float* __restrict__ b2,      // [4]
    float* __restrict__ out)           // [N][B][4]
{
    const int i = blockIdx.x;      // box index = b*N + n
    const int j = threadIdx.x;     // 0..127

    __shared__ float p_s[C_];      // pooled row (256 floats)
    __shared__ float h1_s[D_];     // hidden layer (128 floats)

    p_s[j]        = pooled[i * C_ + j];
    p_s[j + 128]  = pooled[i * C_ + 128 + j];
    __syncthreads();

    // GEMM1: thread j computes h1[j]
    const float4* w1v = (const float4*)(w1 + j * C_);
    const float4* pv  = (const float4*)p_s;
    float s = b1[j];
    #pragma unroll 8
    for (int k = 0; k < C_ / 4; ++k) {
        const float4 wv = w1v[k];
        const float4 pp = pv[k];   // broadcast LDS read (all lanes same addr)
        s += wv.x * pp.x + wv.y * pp.y + wv.z * pp.z + wv.w * pp.w;
    }
    h1_s[j] = s;
    __syncthreads();

    // GEMM2 + sigmoid: wave 0 reduces the 4 outputs
    if (threadIdx.x < 64) {
        const int lane = threadIdx.x;
        #pragma unroll
        for (int jo = 0; jo < 4; ++jo) {
            float part = h1_s[lane]      * w2[jo * D_ + lane]
                       + h1_s[lane + 64] * w2[jo * D_ + lane + 64];
            #pragma unroll
            for (int off = 32; off; off >>= 1)
                part += __shfl_down(part, off);
            if (lane == 0) {
                const int b = i >> 3;   // i / N
                const int n = i & 7;    // i % N
                const float v = part + b2[jo];
                out[(n * B_ + b) * 4 + jo] = 1.0f / (1.0f + expf(-v));
            }
        }
    }
}

extern "C" void kernel_launch(void* const* d_in, const int* in_sizes, int n_in,
                              void* d_out, int out_size, void* d_ws, size_t ws_size,
                              hipStream_t stream) {
    const float* encoded = (const float*)d_in[0];  // [B][C][H][W]
    const float* bboxes  = (const float*)d_in[1];  // [B][N][4]
    const float* w1      = (const float*)d_in[2];  // [D][C]
    const float* b1      = (const float*)d_in[3];  // [D]
    const float* w2      = (const float*)d_in[4];  // [4][D]
    const float* b2      = (const float*)d_in[5];  // [4]
    float* out = (float*)d_out;                    // [N][B][4] = 128 floats
    float* pooled = (float*)d_ws;                  // 32*256 floats = 32 KB

    roi_pool_kernel<<<dim3(B_ * N_ * (C_ / 4)), dim3(256), 0, stream>>>(
        encoded, bboxes, pooled);
    mlp_kernel<<<dim3(B_ * N_), dim3(128), 0, stream>>>(
        pooled, w1, b1, w2, b2, out);
}